// Round 5
// baseline (280.815 us; speedup 1.0000x reference)
//
#include <hip/hip_runtime.h>

typedef unsigned short u16;
typedef unsigned int u32;
typedef unsigned char u8;
typedef signed char i8;

typedef int i32x4 __attribute__((ext_vector_type(4)));

// ---- fused prep: blocks [0,4096) quantize y rows; [4096,8192) quantize w ----
// qy unit p = row*256 + t*8 + j holds logical chunk l = j ^ (row&7) of
// 128-k block t (16 i8, k = t*128 + l*16). sp[m] = s_m/127,
// tv[m] = 128*sum_k(y*rng) + sum_k(y*off).
// wq[n][k] = (i8)(w[k][n] - 128), same swizzled layout on n rows.
__global__ __launch_bounds__(256) void prep_kernel(const float* __restrict__ y,
                                                   const float* __restrict__ w,
                                                   const float* __restrict__ rng,
                                                   const float* __restrict__ off,
                                                   uint4* __restrict__ qy,
                                                   uint4* __restrict__ wq,
                                                   float* __restrict__ sp,
                                                   float* __restrict__ tv) {
    const int tid = threadIdx.x;
    if (blockIdx.x < 4096) {
        // ---- quantize one y row ----
        const int row = blockIdx.x;
        const float* yr = y + (size_t)row * 4096;
        const int base = tid * 16;
        float ysr[16];
        float amax = 0.0f, s1 = 0.0f, s2 = 0.0f;
        #pragma unroll
        for (int ii = 0; ii < 4; ++ii) {
            float4 v = *(const float4*)&yr[base + ii * 4];
            float4 g = *(const float4*)&rng[base + ii * 4];
            float4 o = *(const float4*)&off[base + ii * 4];
            float p0 = v.x * g.x, p1 = v.y * g.y, p2 = v.z * g.z, p3 = v.w * g.w;
            ysr[ii * 4 + 0] = p0; ysr[ii * 4 + 1] = p1;
            ysr[ii * 4 + 2] = p2; ysr[ii * 4 + 3] = p3;
            s1 += p0 + p1 + p2 + p3;
            s2 += v.x * o.x + v.y * o.y + v.z * o.z + v.w * o.w;
            amax = fmaxf(amax, fmaxf(fmaxf(fabsf(p0), fabsf(p1)), fmaxf(fabsf(p2), fabsf(p3))));
        }
        #pragma unroll
        for (int d = 32; d > 0; d >>= 1) {
            amax = fmaxf(amax, __shfl_down(amax, d));
            s1 += __shfl_down(s1, d);
            s2 += __shfl_down(s2, d);
        }
        __shared__ float ra[4], rs1[4], rs2[4];
        const int wv = tid >> 6;
        if ((tid & 63) == 0) { ra[wv] = amax; rs1[wv] = s1; rs2[wv] = s2; }
        __syncthreads();
        const float sm = fmaxf(fmaxf(ra[0], ra[1]), fmaxf(ra[2], ra[3]));
        const float inv = sm > 0.0f ? 127.0f / sm : 0.0f;
        u32 d[4];
        #pragma unroll
        for (int g = 0; g < 4; ++g) {
            u32 b0 = (u8)(i8)(int)rintf(ysr[g * 4 + 0] * inv);
            u32 b1 = (u8)(i8)(int)rintf(ysr[g * 4 + 1] * inv);
            u32 b2 = (u8)(i8)(int)rintf(ysr[g * 4 + 2] * inv);
            u32 b3 = (u8)(i8)(int)rintf(ysr[g * 4 + 3] * inv);
            d[g] = b0 | (b1 << 8) | (b2 << 16) | (b3 << 24);
        }
        const int j = (tid & 7) ^ (row & 7);
        qy[(size_t)row * 256 + (tid >> 3) * 8 + j] = make_uint4(d[0], d[1], d[2], d[3]);
        if (tid == 0) {
            sp[row] = sm / 127.0f;
            tv[row] = 128.0f * (rs1[0] + rs1[1] + rs1[2] + rs1[3])
                            + (rs2[0] + rs2[1] + rs2[2] + rs2[3]);
        }
    } else {
        // ---- transpose+quantize one 64x64 w tile ----
        __shared__ i8 tile[64][68];
        const int b = blockIdx.x - 4096;
        const int n0 = (b & 63) * 64;
        const int k0 = (b >> 6) * 64;
        const int c4 = tid & 15;
        const int r0 = tid >> 4;
        #pragma unroll
        for (int i = 0; i < 4; ++i) {
            int kk = r0 + i * 16;
            float4 v = *(const float4*)&w[(size_t)(k0 + kk) * 4096 + n0 + c4 * 4];
            u32 b0 = (u8)(i8)((int)v.x - 128);
            u32 b1 = (u8)(i8)((int)v.y - 128);
            u32 b2 = (u8)(i8)((int)v.z - 128);
            u32 b3 = (u8)(i8)((int)v.w - 128);
            *(u32*)&tile[kk][c4 * 4] = b0 | (b1 << 8) | (b2 << 16) | (b3 << 24);
        }
        __syncthreads();
        const int nl = tid >> 2;
        const int ci = tid & 3;
        const int l = ((k0 >> 4) & 7) + ci;
        const int j = l ^ ((n0 + nl) & 7);
        u32 d[4];
        #pragma unroll
        for (int g = 0; g < 4; ++g) {
            int kl = ci * 16 + g * 4;
            d[g] = (u32)(u8)tile[kl + 0][nl] | ((u32)(u8)tile[kl + 1][nl] << 8)
                 | ((u32)(u8)tile[kl + 2][nl] << 16) | ((u32)(u8)tile[kl + 3][nl] << 24);
        }
        wq[(size_t)(n0 + nl) * 256 + (k0 >> 7) * 8 + j] = make_uint4(d[0], d[1], d[2], d[3]);
    }
}

// ---- async global->LDS, 16B per lane ----
__device__ inline void gld16(const i8* g, i8* l) {
    __builtin_amdgcn_global_load_lds((const __attribute__((address_space(1))) void*)g,
                                     (__attribute__((address_space(3))) void*)l,
                                     16, 0, 0);
}

// ---- GEMM: Q[m][n] = sum_k qy[m][k]*wq[n][k] (i8->i32 exact), BK=128 ----
// out[m][n] = sp[m]*Q + tv[m]. 256x128 block tile, 4 waves each 128x64
// (8x4 MFMA 16x16x64), 64 MFMA per barrier-pair, 32 K-iterations.
__global__ __launch_bounds__(256) void gemm_kernel(const i8* __restrict__ qy,
                                                   const i8* __restrict__ wq,
                                                   const float* __restrict__ sp,
                                                   const float* __restrict__ tv,
                                                   float* __restrict__ out) {
    __shared__ i8 As[256 * 128];  // 32KB, flat copy of swizzled global
    __shared__ i8 Bs[128 * 128];  // 16KB
    const int bid = blockIdx.x;
    const int xcd = bid & 7;
    const int jj = bid >> 3;                  // 0..63
    const int bn = (xcd * 4 + (jj & 3)) * 128;
    const int bm = (jj >> 2) * 256;

    const int lane = threadIdx.x & 63;
    const int wv = threadIdx.x >> 6;
    const int wm = (wv >> 1) * 128;           // wave computes 128m x 64n
    const int wn = (wv & 1) * 64;
    const int r = lane & 15;
    const int q = lane >> 4;
    const int j0 = q ^ (r & 7);               // stored-unit index of substep-0 chunk

    // staging: A = 32 chunks of 1KB (8 rows x 128B), wave does 8; B = 16, wave does 4
    const int rsub = lane >> 3;
    const int jsub = lane & 7;
    const i8* vA = qy + (size_t)(bm + wv * 64 + rsub) * 4096 + jsub * 16;
    const i8* vB = wq + (size_t)(bn + wv * 32 + rsub) * 4096 + jsub * 16;
    i8* lA = &As[wv * 8 * 1024 + lane * 16];
    i8* lB = &Bs[wv * 4 * 1024 + lane * 16];

    i32x4 acc[8][4] = {};

    for (int kt = 0; kt < 32; ++kt) {
        const int koff = kt * 128;
        #pragma unroll
        for (int c = 0; c < 8; ++c)
            gld16(vA + (size_t)c * 32768 + koff, lA + c * 1024);
        #pragma unroll
        for (int c = 0; c < 4; ++c)
            gld16(vB + (size_t)c * 32768 + koff, lB + c * 1024);
        __syncthreads();

        #pragma unroll
        for (int s = 0; s < 2; ++s) {
            const int js = (j0 ^ (s * 4)) * 16;   // byte offset of this lane's chunk
            i32x4 bfr[4];
            #pragma unroll
            for (int j = 0; j < 4; ++j)
                bfr[j] = *(const i32x4*)&Bs[(wn + j * 16 + r) * 128 + js];
            #pragma unroll
            for (int i = 0; i < 8; ++i) {
                i32x4 af = *(const i32x4*)&As[(wm + i * 16 + r) * 128 + js];
                #pragma unroll
                for (int j = 0; j < 4; ++j)
                    acc[i][j] = __builtin_amdgcn_mfma_i32_16x16x64_i8(af, bfr[j], acc[i][j], 0, 0, 0);
            }
        }
        __syncthreads();
    }

    // C/D layout: n = lane&15, m = (lane>>4)*4 + reg (dtype-independent)
    #pragma unroll
    for (int i = 0; i < 8; ++i) {
        #pragma unroll
        for (int rr = 0; rr < 4; ++rr) {
            const int gm = bm + wm + i * 16 + q * 4 + rr;
            const float sc = sp[gm];
            const float tt = tv[gm];
            #pragma unroll
            for (int j = 0; j < 4; ++j) {
                const int gn = bn + wn + j * 16 + r;
                out[(size_t)gm * 4096 + gn] = sc * (float)acc[i][j][rr] + tt;
            }
        }
    }
}

extern "C" void kernel_launch(void* const* d_in, const int* in_sizes, int n_in,
                              void* d_out, int out_size, void* d_ws, size_t ws_size,
                              hipStream_t stream) {
    const float* y   = (const float*)d_in[0];   // (B,T,C) = 2*2048*4096
    const float* w   = (const float*)d_in[1];   // (C,N)   = 4096*4096
    const float* rng = (const float*)d_in[2];   // (1,1,C) = 4096
    const float* off = (const float*)d_in[3];   // (C,)    = 4096
    float* out = (float*)d_out;                 // (B,T,N) fp32

    i8* qy = (i8*)d_ws;                         // 16MB swizzled i8 [m][k]
    i8* wq = qy + (size_t)4096 * 4096;          // 16MB swizzled i8 [n][k]
    float* sp = (float*)(wq + (size_t)4096 * 4096);  // 16KB per-row scale
    float* tv = sp + 4096;                           // 16KB per-row additive term

    prep_kernel<<<8192, 256, 0, stream>>>(y, w, rng, off, (uint4*)qy, (uint4*)wq, sp, tv);
    gemm_kernel<<<512, 256, 0, stream>>>(qy, wq, sp, tv, out);
}